// Round 1
// baseline (331.536 us; speedup 1.0000x reference)
//
#include <hip/hip_runtime.h>
#include <math.h>

// Problem constants
#define B_   2
#define S_   256
#define E_   512
#define H_   8
#define DH_  64
#define LCACHE 6144   // TC*H = 768*8
#define LNEW   2048   // S*H
#define NSPLIT 4
#define LSPLIT 2048   // 8192/4

// ---------------------------------------------------------------------------
// Tiled NT GEMM body: C[M,N] = A[M,512] @ W[N,512]^T + bias, M=N=K=512.
// 64x64 tile per block, 256 threads, 4x4 per thread, transposed LDS tiles.
// ---------------------------------------------------------------------------
__device__ __forceinline__ void gemm512_body(
    const float* __restrict__ A, const float* __restrict__ W,
    const float* __restrict__ bias, float* __restrict__ C)
{
    __shared__ float AsT[16][68];   // [k][m], pad 68 (mult of 4 for b128 reads)
    __shared__ float WsT[16][68];   // [k][n]
    const int tid = threadIdx.x;
    const int row0 = blockIdx.y * 64;
    const int col0 = blockIdx.x * 64;
    const int tx = tid & 15;        // col group
    const int ty = tid >> 4;        // row group
    const int lr = tid >> 2;        // staging: row within tile (0..63)
    const int lc = (tid & 3) << 2;  // staging: k offset (0,4,8,12)

    float acc[4][4] = {};

    for (int k0 = 0; k0 < 512; k0 += 16) {
        const float4 av = *reinterpret_cast<const float4*>(&A[(row0 + lr) * 512 + k0 + lc]);
        const float4 wv = *reinterpret_cast<const float4*>(&W[(col0 + lr) * 512 + k0 + lc]);
        __syncthreads();            // previous iteration's compute done
        AsT[lc+0][lr]=av.x; AsT[lc+1][lr]=av.y; AsT[lc+2][lr]=av.z; AsT[lc+3][lr]=av.w;
        WsT[lc+0][lr]=wv.x; WsT[lc+1][lr]=wv.y; WsT[lc+2][lr]=wv.z; WsT[lc+3][lr]=wv.w;
        __syncthreads();
#pragma unroll
        for (int kk = 0; kk < 16; ++kk) {
            const float4 a4 = *reinterpret_cast<const float4*>(&AsT[kk][ty << 2]);
            const float4 b4 = *reinterpret_cast<const float4*>(&WsT[kk][tx << 2]);
            const float aa[4] = {a4.x, a4.y, a4.z, a4.w};
            const float bb[4] = {b4.x, b4.y, b4.z, b4.w};
#pragma unroll
            for (int i = 0; i < 4; ++i)
#pragma unroll
                for (int j = 0; j < 4; ++j)
                    acc[i][j] = fmaf(aa[i], bb[j], acc[i][j]);
        }
    }

    const float4 bv4 = *reinterpret_cast<const float4*>(&bias[col0 + (tx << 2)]);
    const float bbb[4] = {bv4.x, bv4.y, bv4.z, bv4.w};
#pragma unroll
    for (int i = 0; i < 4; ++i) {
        float4 o;
        o.x = acc[i][0] + bbb[0];
        o.y = acc[i][1] + bbb[1];
        o.z = acc[i][2] + bbb[2];
        o.w = acc[i][3] + bbb[3];
        *reinterpret_cast<float4*>(&C[(row0 + (ty << 2) + i) * 512 + col0 + (tx << 2)]) = o;
    }
}

// Fused QKV projection: blockIdx.z selects which weight/output.
__global__ __launch_bounds__(256) void proj_qkv(
    const float* __restrict__ x,
    const float* __restrict__ Wq, const float* __restrict__ bq,
    const float* __restrict__ Wk, const float* __restrict__ bk,
    const float* __restrict__ Wv, const float* __restrict__ bv,
    float* __restrict__ Qp, float* __restrict__ Kn, float* __restrict__ Vn)
{
    const float* W; const float* bias; float* C;
    if (blockIdx.z == 0)      { W = Wq; bias = bq; C = Qp; }
    else if (blockIdx.z == 1) { W = Wk; bias = bk; C = Kn; }
    else                      { W = Wv; bias = bv; C = Vn; }
    gemm512_body(x, W, bias, C);
}

__global__ __launch_bounds__(256) void proj_o(
    const float* __restrict__ Ao, const float* __restrict__ Wo,
    const float* __restrict__ bo, float* __restrict__ out)
{
    gemm512_body(Ao, Wo, bo, out);
}

// ---------------------------------------------------------------------------
// Flash attention partial: 32 query rows per block, 64-key tiles, 4-way L
// split. Q rows are the flat (s,h) rows of Qp[B, S*H, DH]; all rows attend
// over the same K/V rows (reference broadcasts K over heads).
// Thread map (256 thr): tcol=tid&15 (key/dim cols, x4), trow=tid>>4 (rows, x2).
// ---------------------------------------------------------------------------
__global__ __launch_bounds__(256) void attn_partial(
    const float* __restrict__ Qp,  // [B, 2048, 64]
    const float* __restrict__ Kc,  // [B, 6144, 64]
    const float* __restrict__ Kn,  // [B, 2048, 64]
    const float* __restrict__ Vc,
    const float* __restrict__ Vn,
    float* __restrict__ Pacc, float* __restrict__ Pm, float* __restrict__ Pl)
{
    __shared__ float QsT[64][34];  // [k][r], Q pre-scaled by 1/sqrt(DH)
    __shared__ float KsT[64][68];  // [k][l]
    __shared__ float Vs [64][68];  // [l][d]
    __shared__ float PT [64][34];  // [l][r]

    const int tid   = threadIdx.x;
    const int split = blockIdx.x;  // 0..3
    const int qt    = blockIdx.y;  // 0..63
    const int b     = blockIdx.z;  // 0..1

    // stage Q tile (32x64) transposed, pre-scaled
    {
        const float* Qb = Qp + ((size_t)b * LNEW + qt * 32) * 64;
        const int r = tid >> 3, k8 = (tid & 7) * 8;
        const float4 v0 = *reinterpret_cast<const float4*>(&Qb[r * 64 + k8]);
        const float4 v1 = *reinterpret_cast<const float4*>(&Qb[r * 64 + k8 + 4]);
        const float sc = 0.125f;   // 1/sqrt(64)
        QsT[k8+0][r]=v0.x*sc; QsT[k8+1][r]=v0.y*sc; QsT[k8+2][r]=v0.z*sc; QsT[k8+3][r]=v0.w*sc;
        QsT[k8+4][r]=v1.x*sc; QsT[k8+5][r]=v1.y*sc; QsT[k8+6][r]=v1.z*sc; QsT[k8+7][r]=v1.w*sc;
    }

    const int tcol = tid & 15, trow = tid >> 4;
    float m0 = -INFINITY, m1 = -INFINITY;
    float ls0 = 0.f, ls1 = 0.f;
    float acc0[4] = {}, acc1[4] = {};

    for (int t = 0; t < 32; ++t) {
        const int l0 = split * LSPLIT + t * 64;
        const float* Ksrc;
        const float* Vsrc;
        if (l0 < LCACHE) {
            Ksrc = Kc + ((size_t)b * LCACHE + l0) * 64;
            Vsrc = Vc + ((size_t)b * LCACHE + l0) * 64;
        } else {
            Ksrc = Kn + ((size_t)b * LNEW + (l0 - LCACHE)) * 64;
            Vsrc = Vn + ((size_t)b * LNEW + (l0 - LCACHE)) * 64;
        }
        __syncthreads();           // previous PV done before overwrite
#pragma unroll
        for (int rep = 0; rep < 4; ++rep) {
            const int flat4 = rep * 256 + tid;       // 0..1023 float4 slots
            const int l = flat4 >> 4, k4 = (flat4 & 15) << 2;
            const float4 kv = *reinterpret_cast<const float4*>(&Ksrc[l * 64 + k4]);
            const float4 vv = *reinterpret_cast<const float4*>(&Vsrc[l * 64 + k4]);
            KsT[k4+0][l]=kv.x; KsT[k4+1][l]=kv.y; KsT[k4+2][l]=kv.z; KsT[k4+3][l]=kv.w;
            *reinterpret_cast<float4*>(&Vs[l][k4]) = vv;
        }
        __syncthreads();

        // scores: rows trow*2+{0,1}, keys tcol*4+{0..3}
        float s0[4] = {}, s1[4] = {};
#pragma unroll 16
        for (int kk = 0; kk < 64; ++kk) {
            const float2 a  = *reinterpret_cast<const float2*>(&QsT[kk][trow << 1]);
            const float4 k4 = *reinterpret_cast<const float4*>(&KsT[kk][tcol << 2]);
            s0[0] = fmaf(a.x, k4.x, s0[0]); s0[1] = fmaf(a.x, k4.y, s0[1]);
            s0[2] = fmaf(a.x, k4.z, s0[2]); s0[3] = fmaf(a.x, k4.w, s0[3]);
            s1[0] = fmaf(a.y, k4.x, s1[0]); s1[1] = fmaf(a.y, k4.y, s1[1]);
            s1[2] = fmaf(a.y, k4.z, s1[2]); s1[3] = fmaf(a.y, k4.w, s1[3]);
        }

        // online softmax, row 0
        {
            float tmax = fmaxf(fmaxf(s0[0], s0[1]), fmaxf(s0[2], s0[3]));
#pragma unroll
            for (int off = 1; off < 16; off <<= 1) tmax = fmaxf(tmax, __shfl_xor(tmax, off));
            const float mn = fmaxf(m0, tmax);
            const float scale = __expf(m0 - mn);
            float p[4], ps = 0.f;
#pragma unroll
            for (int j = 0; j < 4; ++j) { p[j] = __expf(s0[j] - mn); ps += p[j]; }
#pragma unroll
            for (int off = 1; off < 16; off <<= 1) ps += __shfl_xor(ps, off);
            ls0 = ls0 * scale + ps; m0 = mn;
#pragma unroll
            for (int j = 0; j < 4; ++j) { acc0[j] *= scale; PT[(tcol << 2) + j][(trow << 1) + 0] = p[j]; }
        }
        // row 1
        {
            float tmax = fmaxf(fmaxf(s1[0], s1[1]), fmaxf(s1[2], s1[3]));
#pragma unroll
            for (int off = 1; off < 16; off <<= 1) tmax = fmaxf(tmax, __shfl_xor(tmax, off));
            const float mn = fmaxf(m1, tmax);
            const float scale = __expf(m1 - mn);
            float p[4], ps = 0.f;
#pragma unroll
            for (int j = 0; j < 4; ++j) { p[j] = __expf(s1[j] - mn); ps += p[j]; }
#pragma unroll
            for (int off = 1; off < 16; off <<= 1) ps += __shfl_xor(ps, off);
            ls1 = ls1 * scale + ps; m1 = mn;
#pragma unroll
            for (int j = 0; j < 4; ++j) { acc1[j] *= scale; PT[(tcol << 2) + j][(trow << 1) + 1] = p[j]; }
        }
        __syncthreads();

        // PV: acc[i][j] += sum_l PT[l][trow*2+i] * Vs[l][tcol*4+j]
#pragma unroll 16
        for (int l = 0; l < 64; ++l) {
            const float2 a  = *reinterpret_cast<const float2*>(&PT[l][trow << 1]);
            const float4 vv = *reinterpret_cast<const float4*>(&Vs[l][tcol << 2]);
            acc0[0] = fmaf(a.x, vv.x, acc0[0]); acc0[1] = fmaf(a.x, vv.y, acc0[1]);
            acc0[2] = fmaf(a.x, vv.z, acc0[2]); acc0[3] = fmaf(a.x, vv.w, acc0[3]);
            acc1[0] = fmaf(a.y, vv.x, acc1[0]); acc1[1] = fmaf(a.y, vv.y, acc1[1]);
            acc1[2] = fmaf(a.y, vv.z, acc1[2]); acc1[3] = fmaf(a.y, vv.w, acc1[3]);
        }
    }

    // write partials
    const size_t base = ((size_t)(b * 64 + qt) * NSPLIT + split);
#pragma unroll
    for (int j = 0; j < 4; ++j) {
        Pacc[base * 2048 + ((trow << 1) + 0) * 64 + (tcol << 2) + j] = acc0[j];
        Pacc[base * 2048 + ((trow << 1) + 1) * 64 + (tcol << 2) + j] = acc1[j];
    }
    if (tcol == 0) {
        Pm[base * 32 + (trow << 1) + 0] = m0;
        Pm[base * 32 + (trow << 1) + 1] = m1;
        Pl[base * 32 + (trow << 1) + 0] = ls0;
        Pl[base * 32 + (trow << 1) + 1] = ls1;
    }
}

// Merge the 4 split partials per query row.
__global__ __launch_bounds__(256) void attn_combine(
    const float* __restrict__ Pacc, const float* __restrict__ Pm,
    const float* __restrict__ Pl, float* __restrict__ Ao)
{
    const int tid = threadIdx.x;
    const int row = blockIdx.x * 4 + (tid >> 6);   // 0..4095 (b*2048 + q)
    const int d   = tid & 63;
    const int b   = row >> 11;
    const int q   = row & 2047;
    const int qt  = q >> 5, r = q & 31;
    const size_t base0 = (size_t)(b * 64 + qt) * NSPLIT;

    float ms[NSPLIT];
    float mstar = -INFINITY;
#pragma unroll
    for (int sp = 0; sp < NSPLIT; ++sp) {
        ms[sp] = Pm[(base0 + sp) * 32 + r];
        mstar = fmaxf(mstar, ms[sp]);
    }
    float num = 0.f, den = 0.f;
#pragma unroll
    for (int sp = 0; sp < NSPLIT; ++sp) {
        const float e = __expf(ms[sp] - mstar);
        num = fmaf(Pacc[(base0 + sp) * 2048 + r * 64 + d], e, num);
        den = fmaf(Pl[(base0 + sp) * 32 + r], e, den);
    }
    Ao[(size_t)row * 64 + d] = num / den;
}

// ---------------------------------------------------------------------------
extern "C" void kernel_launch(void* const* d_in, const int* in_sizes, int n_in,
                              void* d_out, int out_size, void* d_ws, size_t ws_size,
                              hipStream_t stream)
{
    const float* x  = (const float*)d_in[0];
    const float* kc = (const float*)d_in[1];
    const float* vc = (const float*)d_in[2];
    const float* Wq = (const float*)d_in[3];
    const float* bq = (const float*)d_in[4];
    const float* Wk = (const float*)d_in[5];
    const float* bk = (const float*)d_in[6];
    const float* Wv = (const float*)d_in[7];
    const float* bv = (const float*)d_in[8];
    const float* Wo = (const float*)d_in[9];
    const float* bo = (const float*)d_in[10];
    float* out = (float*)d_out;

    float* ws   = (float*)d_ws;
    float* Qp   = ws;                 // 262144
    float* Kn   = ws + 262144;        // 262144
    float* Vn   = ws + 524288;        // 262144
    float* Ao   = ws + 786432;        // 262144
    float* Pacc = ws + 1048576;       // 1048576
    float* Pm   = ws + 2097152;       // 16384
    float* Pl   = ws + 2113536;       // 16384

    // 1. QKV projections (fused across z)
    proj_qkv<<<dim3(8, 8, 3), 256, 0, stream>>>(x, Wq, bq, Wk, bk, Wv, bv, Qp, Kn, Vn);

    // 2. Flash attention partials: grid (split, qtile, batch) = 512 blocks
    attn_partial<<<dim3(NSPLIT, 64, B_), 256, 0, stream>>>(Qp, kc, Kn, vc, Vn, Pacc, Pm, Pl);

    // 3. Combine splits
    attn_combine<<<dim3(1024), 256, 0, stream>>>(Pacc, Pm, Pl, Ao);

    // 4. Output projection
    proj_o<<<dim3(8, 8, 1), 256, 0, stream>>>(Ao, Wo, bo, out);
}

// Round 2
// 190.598 us; speedup vs baseline: 1.7395x; 1.7395x over previous
//
#include <hip/hip_runtime.h>
#include <math.h>

// Problem constants
#define B_   2
#define S_   256
#define E_   512
#define H_   8
#define DH_  64
#define LTOT   8192   // total KV rows per batch (TC*H + S*H)
#define LCACHE 6144   // TC*H
#define LNEW   2048   // S*H
#define NSPLIT 8      // L-splits across blocks (x4 waves inside block)

typedef __attribute__((ext_vector_type(8))) short bf16x8;
typedef __attribute__((ext_vector_type(4))) float f32x4;

__device__ __forceinline__ ushort f2bf(float f) {             // RTN f32->bf16
    unsigned u = __float_as_uint(f);
    return (ushort)((u + 0x7fffu + ((u >> 16) & 1u)) >> 16);
}

// ---------------------------------------------------------------------------
// Tiled NT fp32 GEMM body (unchanged from round 0): C = A@W^T + bias, 512^3.
// ---------------------------------------------------------------------------
__device__ __forceinline__ void gemm512_body(
    const float* __restrict__ A, const float* __restrict__ W,
    const float* __restrict__ bias, float* __restrict__ C)
{
    __shared__ float AsT[16][68];
    __shared__ float WsT[16][68];
    const int tid = threadIdx.x;
    const int row0 = blockIdx.y * 64;
    const int col0 = blockIdx.x * 64;
    const int tx = tid & 15;
    const int ty = tid >> 4;
    const int lr = tid >> 2;
    const int lc = (tid & 3) << 2;

    float acc[4][4] = {};

    for (int k0 = 0; k0 < 512; k0 += 16) {
        const float4 av = *reinterpret_cast<const float4*>(&A[(row0 + lr) * 512 + k0 + lc]);
        const float4 wv = *reinterpret_cast<const float4*>(&W[(col0 + lr) * 512 + k0 + lc]);
        __syncthreads();
        AsT[lc+0][lr]=av.x; AsT[lc+1][lr]=av.y; AsT[lc+2][lr]=av.z; AsT[lc+3][lr]=av.w;
        WsT[lc+0][lr]=wv.x; WsT[lc+1][lr]=wv.y; WsT[lc+2][lr]=wv.z; WsT[lc+3][lr]=wv.w;
        __syncthreads();
#pragma unroll
        for (int kk = 0; kk < 16; ++kk) {
            const float4 a4 = *reinterpret_cast<const float4*>(&AsT[kk][ty << 2]);
            const float4 b4 = *reinterpret_cast<const float4*>(&WsT[kk][tx << 2]);
            const float aa[4] = {a4.x, a4.y, a4.z, a4.w};
            const float bb[4] = {b4.x, b4.y, b4.z, b4.w};
#pragma unroll
            for (int i = 0; i < 4; ++i)
#pragma unroll
                for (int j = 0; j < 4; ++j)
                    acc[i][j] = fmaf(aa[i], bb[j], acc[i][j]);
        }
    }

    const float4 bv4 = *reinterpret_cast<const float4*>(&bias[col0 + (tx << 2)]);
    const float bbb[4] = {bv4.x, bv4.y, bv4.z, bv4.w};
#pragma unroll
    for (int i = 0; i < 4; ++i) {
        float4 o;
        o.x = acc[i][0] + bbb[0];
        o.y = acc[i][1] + bbb[1];
        o.z = acc[i][2] + bbb[2];
        o.w = acc[i][3] + bbb[3];
        *reinterpret_cast<float4*>(&C[(row0 + (ty << 2) + i) * 512 + col0 + (tx << 2)]) = o;
    }
}

__global__ __launch_bounds__(256) void proj_qkv(
    const float* __restrict__ x,
    const float* __restrict__ Wq, const float* __restrict__ bq,
    const float* __restrict__ Wk, const float* __restrict__ bk,
    const float* __restrict__ Wv, const float* __restrict__ bv,
    float* __restrict__ Qp, float* __restrict__ Kn, float* __restrict__ Vn)
{
    const float* W; const float* bias; float* C;
    if (blockIdx.z == 0)      { W = Wq; bias = bq; C = Qp; }
    else if (blockIdx.z == 1) { W = Wk; bias = bk; C = Kn; }
    else                      { W = Wv; bias = bv; C = Vn; }
    gemm512_body(x, W, bias, C);
}

__global__ __launch_bounds__(256) void proj_o(
    const float* __restrict__ Ao, const float* __restrict__ Wo,
    const float* __restrict__ bo, float* __restrict__ out)
{
    gemm512_body(Ao, Wo, bo, out);
}

// ---------------------------------------------------------------------------
// prep_hilo: fp32 -> bf16 hi/lo for Q (pre-scaled by 1/8) and K (cache+new
// concatenated to [B][8192][64]).  grid (64, B, 3)
// ---------------------------------------------------------------------------
__global__ __launch_bounds__(256) void prep_hilo(
    const float* __restrict__ Qp, const float* __restrict__ Kc, const float* __restrict__ Kn,
    ushort* __restrict__ Qhi, ushort* __restrict__ Qlo,
    ushort* __restrict__ Khi, ushort* __restrict__ Klo)
{
    const int z = blockIdx.z, y = blockIdx.y;
    const float* src; ushort* dhi; ushort* dlo; int n4; float sc;
    if (z == 0)      { src = Qp + y*131072; dhi = Qhi + y*131072;          dlo = Qlo + y*131072;          n4 = 32768; sc = 0.125f; }
    else if (z == 1) { src = Kc + y*393216; dhi = Khi + y*524288;          dlo = Klo + y*524288;          n4 = 98304; sc = 1.0f;   }
    else             { src = Kn + y*131072; dhi = Khi + y*524288 + 393216; dlo = Klo + y*524288 + 393216; n4 = 32768; sc = 1.0f;   }

    for (int i = blockIdx.x * 256 + threadIdx.x; i < n4; i += gridDim.x * 256) {
        float4 v = reinterpret_cast<const float4*>(src)[i];
        v.x *= sc; v.y *= sc; v.z *= sc; v.w *= sc;
        ushort4 h, l;
        h.x = f2bf(v.x); l.x = f2bf(v.x - __uint_as_float((unsigned)h.x << 16));
        h.y = f2bf(v.y); l.y = f2bf(v.y - __uint_as_float((unsigned)h.y << 16));
        h.z = f2bf(v.z); l.z = f2bf(v.z - __uint_as_float((unsigned)h.z << 16));
        h.w = f2bf(v.w); l.w = f2bf(v.w - __uint_as_float((unsigned)h.w << 16));
        reinterpret_cast<ushort4*>(dhi)[i] = h;
        reinterpret_cast<ushort4*>(dlo)[i] = l;
    }
}

// ---------------------------------------------------------------------------
// vt_kernel: V (cache+new, fp32 [key][64]) -> Vt bf16 [B][64][8192] (dim-major)
// grid (128, B); 64-key x 64-dim tile per block via LDS transpose.
// ---------------------------------------------------------------------------
__global__ __launch_bounds__(256) void vt_kernel(
    const float* __restrict__ Vc, const float* __restrict__ Vn, ushort* __restrict__ Vt)
{
    __shared__ ushort sT[64][68];   // [dim][key]
    const int kt = blockIdx.x, b = blockIdx.y, tid = threadIdx.x;
    const int key0 = kt * 64;
#pragma unroll
    for (int it = 0; it < 4; ++it) {
        const int id = it * 256 + tid;          // 0..1023 float4 slots
        const int row = id >> 4, c4 = (id & 15) << 2;
        const int key = key0 + row;
        const float* src = (key < LCACHE)
            ? (Vc + ((size_t)b * LCACHE + key) * 64 + c4)
            : (Vn + ((size_t)b * LNEW + (key - LCACHE)) * 64 + c4);
        const float4 v = *reinterpret_cast<const float4*>(src);
        sT[c4+0][row] = f2bf(v.x); sT[c4+1][row] = f2bf(v.y);
        sT[c4+2][row] = f2bf(v.z); sT[c4+3][row] = f2bf(v.w);
    }
    __syncthreads();
#pragma unroll
    for (int it = 0; it < 4; ++it) {
        const int id = it * 256 + tid;          // 0..1023 ushort4 slots
        const int d = id >> 4, ku = (id & 15) << 2;
        ushort4 o;
        o.x = sT[d][ku]; o.y = sT[d][ku+1]; o.z = sT[d][ku+2]; o.w = sT[d][ku+3];
        *reinterpret_cast<ushort4*>(&Vt[((size_t)b * 64 + d) * LTOT + key0 + ku]) = o;
    }
}

// ---------------------------------------------------------------------------
// attn_mfma: flash attention with MFMA.
//   - computes S^T = K . Q^T (A=K rows, B=Q rows), so each lane's 8 score
//     regs (2 subtiles x 4) all belong to ONE q-row (col = lane&15).
//   - K A-frag rows loaded in permuted order key = k0 + st*4 + (lr&3) +
//     (lr>>2)*8 so the exp'd scores form the PV 16x16x32 B-fragment in-lane.
//   - PV: O^T = V^T . P^T, A-frags read 16B-contiguous from Vt.
// Each wave: 32 q-rows (2 qtiles), private 256-key chunk; 4 waves/block
// combined in LDS; NSPLIT=8 chunks combined by combine2.
// grid (NSPLIT, 64, B), 256 threads.
// ---------------------------------------------------------------------------
__global__ __launch_bounds__(256) void attn_mfma(
    const ushort* __restrict__ Qhi, const ushort* __restrict__ Qlo,
    const ushort* __restrict__ Khi, const ushort* __restrict__ Klo,
    const ushort* __restrict__ Vt,
    float* __restrict__ Pacc, float* __restrict__ Pm, float* __restrict__ Pl)
{
    __shared__ float sAcc[4][32][68];
    __shared__ float sM[4][32];
    __shared__ float sL[4][32];

    const int tid = threadIdx.x;
    const int wv = tid >> 6, lane = tid & 63;
    const int lr = lane & 15, lg = lane >> 4;
    const int split = blockIdx.x, qb = blockIdx.y, b = blockIdx.z;

    // Q fragments (loop-invariant): lane holds Q[qrow=lr][h*32 + lg*8 .. +7]
    bf16x8 qh[2][2], ql[2][2];
    {
        const int qrow0 = b * 2048 + qb * 32 + lr;
#pragma unroll
        for (int q = 0; q < 2; ++q)
#pragma unroll
            for (int h = 0; h < 2; ++h) {
                const int off = (qrow0 + q * 16) * 64 + h * 32 + lg * 8;
                qh[q][h] = *reinterpret_cast<const bf16x8*>(Qhi + off);
                ql[q][h] = *reinterpret_cast<const bf16x8*>(Qlo + off);
            }
    }

    const int kchunk = LTOT / NSPLIT / 4;            // 256 keys per wave
    const int kbase  = split * (LTOT / NSPLIT) + wv * kchunk;
    const int NT     = kchunk / 32;                  // 8 tiles of 32 keys
    const int krow0  = kbase + (lr & 3) + ((lr >> 2) << 3);   // permuted A row
    const ushort* kh_p = Khi + (size_t)b * LTOT * 64 + krow0 * 64 + lg * 8;
    const ushort* kl_p = Klo + (size_t)b * LTOT * 64 + krow0 * 64 + lg * 8;
    const ushort* vt_p = Vt  + (size_t)b * 64 * LTOT + (size_t)lr * LTOT + kbase + lg * 8;

    f32x4 acc[2][4];
#pragma unroll
    for (int q = 0; q < 2; ++q)
#pragma unroll
        for (int dt = 0; dt < 4; ++dt) acc[q][dt] = (f32x4){0.f, 0.f, 0.f, 0.f};
    float m0 = -INFINITY, m1 = -INFINITY, l0 = 0.f, l1 = 0.f;

    for (int t = 0; t < NT; ++t) {
        const ushort* kh = kh_p + t * 32 * 64;
        const ushort* kl = kl_p + t * 32 * 64;
        bf16x8 kf[2][2], lf[2][2], vf[4];
#pragma unroll
        for (int st = 0; st < 2; ++st)
#pragma unroll
            for (int h = 0; h < 2; ++h) {
                kf[st][h] = *reinterpret_cast<const bf16x8*>(kh + st * 4 * 64 + h * 32);
                lf[st][h] = *reinterpret_cast<const bf16x8*>(kl + st * 4 * 64 + h * 32);
            }
#pragma unroll
        for (int dt = 0; dt < 4; ++dt)
            vf[dt] = *reinterpret_cast<const bf16x8*>(vt_p + (size_t)dt * 16 * LTOT + t * 32);

#pragma unroll
        for (int q = 0; q < 2; ++q) {
            f32x4 s0 = {0.f,0.f,0.f,0.f}, s1 = {0.f,0.f,0.f,0.f};
#pragma unroll
            for (int h = 0; h < 2; ++h) {
                s0 = __builtin_amdgcn_mfma_f32_16x16x32_bf16(kf[0][h], qh[q][h], s0, 0, 0, 0);
                s0 = __builtin_amdgcn_mfma_f32_16x16x32_bf16(kf[0][h], ql[q][h], s0, 0, 0, 0);
                s0 = __builtin_amdgcn_mfma_f32_16x16x32_bf16(lf[0][h], qh[q][h], s0, 0, 0, 0);
                s1 = __builtin_amdgcn_mfma_f32_16x16x32_bf16(kf[1][h], qh[q][h], s1, 0, 0, 0);
                s1 = __builtin_amdgcn_mfma_f32_16x16x32_bf16(kf[1][h], ql[q][h], s1, 0, 0, 0);
                s1 = __builtin_amdgcn_mfma_f32_16x16x32_bf16(lf[1][h], qh[q][h], s1, 0, 0, 0);
            }
            float& mq = q ? m1 : m0;
            float& lq = q ? l1 : l0;
            float tm = fmaxf(fmaxf(fmaxf(s0.x, s0.y), fmaxf(s0.z, s0.w)),
                             fmaxf(fmaxf(s1.x, s1.y), fmaxf(s1.z, s1.w)));
            tm = fmaxf(tm, __shfl_xor(tm, 16));
            tm = fmaxf(tm, __shfl_xor(tm, 32));
            const float mn = fmaxf(mq, tm);
            const float corr = __expf(mq - mn);
            float p[8];
            p[0] = __expf(s0.x - mn); p[1] = __expf(s0.y - mn);
            p[2] = __expf(s0.z - mn); p[3] = __expf(s0.w - mn);
            p[4] = __expf(s1.x - mn); p[5] = __expf(s1.y - mn);
            p[6] = __expf(s1.z - mn); p[7] = __expf(s1.w - mn);
            float ps = ((p[0]+p[1]) + (p[2]+p[3])) + ((p[4]+p[5]) + (p[6]+p[7]));
            ps += __shfl_xor(ps, 16);
            ps += __shfl_xor(ps, 32);
            lq = lq * corr + ps; mq = mn;

            union { bf16x8 v; ushort u[8]; } pf;
#pragma unroll
            for (int j = 0; j < 8; ++j) pf.u[j] = f2bf(p[j]);
#pragma unroll
            for (int dt = 0; dt < 4; ++dt) {
                f32x4 a = acc[q][dt];
                a.x *= corr; a.y *= corr; a.z *= corr; a.w *= corr;
                acc[q][dt] = __builtin_amdgcn_mfma_f32_16x16x32_bf16(vf[dt], pf.v, a, 0, 0, 0);
            }
        }
    }

    // per-wave partials -> LDS   (C/D: col=lane&15 -> qrow, row -> dim)
#pragma unroll
    for (int q = 0; q < 2; ++q)
#pragma unroll
        for (int dt = 0; dt < 4; ++dt) {
            float4 o; o.x = acc[q][dt].x; o.y = acc[q][dt].y; o.z = acc[q][dt].z; o.w = acc[q][dt].w;
            *reinterpret_cast<float4*>(&sAcc[wv][q * 16 + lr][dt * 16 + lg * 4]) = o;
        }
    if (lg == 0) {
        sM[wv][lr] = m0;      sM[wv][16 + lr] = m1;
        sL[wv][lr] = l0;      sL[wv][16 + lr] = l1;
    }
    __syncthreads();

    // combine 4 waves: thread -> (qrow, 8-dim group)
    {
        const int qrow = tid >> 3, dg = tid & 7;
        float mw[4], ms = -INFINITY;
#pragma unroll
        for (int w = 0; w < 4; ++w) { mw[w] = sM[w][qrow]; ms = fmaxf(ms, mw[w]); }
        float den = 0.f;
        float num[8] = {};
#pragma unroll
        for (int w = 0; w < 4; ++w) {
            const float e = __expf(mw[w] - ms);
            den = fmaf(sL[w][qrow], e, den);
            const float4 a0 = *reinterpret_cast<const float4*>(&sAcc[w][qrow][dg * 8]);
            const float4 a1 = *reinterpret_cast<const float4*>(&sAcc[w][qrow][dg * 8 + 4]);
            num[0] = fmaf(a0.x, e, num[0]); num[1] = fmaf(a0.y, e, num[1]);
            num[2] = fmaf(a0.z, e, num[2]); num[3] = fmaf(a0.w, e, num[3]);
            num[4] = fmaf(a1.x, e, num[4]); num[5] = fmaf(a1.y, e, num[5]);
            num[6] = fmaf(a1.z, e, num[6]); num[7] = fmaf(a1.w, e, num[7]);
        }
        const int row_g = b * 2048 + qb * 32 + qrow;
        float* dst = Pacc + ((size_t)row_g * NSPLIT + split) * 64 + dg * 8;
        float4 o0 = {num[0], num[1], num[2], num[3]};
        float4 o1 = {num[4], num[5], num[6], num[7]};
        *reinterpret_cast<float4*>(dst)     = o0;
        *reinterpret_cast<float4*>(dst + 4) = o1;
        if (dg == 0) {
            Pm[(size_t)row_g * NSPLIT + split] = ms;
            Pl[(size_t)row_g * NSPLIT + split] = den;
        }
    }
}

// Combine the NSPLIT partial chunks per q-row.
__global__ __launch_bounds__(256) void combine2(
    const float* __restrict__ Pacc, const float* __restrict__ Pm,
    const float* __restrict__ Pl, float* __restrict__ Ao)
{
    const int g = blockIdx.x * 256 + threadIdx.x;   // 0..262143
    const int row = g >> 6, d = g & 63;
    float mv[NSPLIT], ms = -INFINITY;
#pragma unroll
    for (int sp = 0; sp < NSPLIT; ++sp) { mv[sp] = Pm[row * NSPLIT + sp]; ms = fmaxf(ms, mv[sp]); }
    float num = 0.f, den = 0.f;
#pragma unroll
    for (int sp = 0; sp < NSPLIT; ++sp) {
        const float e = __expf(mv[sp] - ms);
        num = fmaf(Pacc[((size_t)row * NSPLIT + sp) * 64 + d], e, num);
        den = fmaf(Pl[row * NSPLIT + sp], e, den);
    }
    Ao[g] = num / den;
}

// ---------------------------------------------------------------------------
extern "C" void kernel_launch(void* const* d_in, const int* in_sizes, int n_in,
                              void* d_out, int out_size, void* d_ws, size_t ws_size,
                              hipStream_t stream)
{
    const float* x  = (const float*)d_in[0];
    const float* kc = (const float*)d_in[1];
    const float* vc = (const float*)d_in[2];
    const float* Wq = (const float*)d_in[3];
    const float* bq = (const float*)d_in[4];
    const float* Wk = (const float*)d_in[5];
    const float* bk = (const float*)d_in[6];
    const float* Wv = (const float*)d_in[7];
    const float* bv = (const float*)d_in[8];
    const float* Wo = (const float*)d_in[9];
    const float* bo = (const float*)d_in[10];
    float* out = (float*)d_out;

    float* ws   = (float*)d_ws;
    float* Qp   = ws;                  //  262144 f
    float* Kn   = ws +  262144;        //  262144 f
    float* Vn   = ws +  524288;        //  262144 f
    float* Ao   = ws +  786432;        //  262144 f
    float* Pacc = ws + 1048576;        // 2097152 f
    float* Pm   = ws + 3145728;        //   32768 f
    float* Pl   = ws + 3178496;        //   32768 f
    ushort* us  = (ushort*)(ws + 3211264);
    ushort* Qhi = us;                  //  262144 us
    ushort* Qlo = us +  262144;        //  262144 us
    ushort* Khi = us +  524288;        // 1048576 us
    ushort* Klo = us + 1572864;        // 1048576 us
    ushort* Vt  = us + 2621440;        // 1048576 us

    // 1. QKV projections (fp32)
    proj_qkv<<<dim3(8, 8, 3), 256, 0, stream>>>(x, Wq, bq, Wk, bk, Wv, bv, Qp, Kn, Vn);

    // 2. Convert Q/K to bf16 hi/lo, transpose V to bf16 dim-major
    prep_hilo<<<dim3(64, B_, 3), 256, 0, stream>>>(Qp, kc, Kn, Qhi, Qlo, Khi, Klo);
    vt_kernel<<<dim3(128, B_), 256, 0, stream>>>(vc, Vn, Vt);

    // 3. MFMA flash attention partials
    attn_mfma<<<dim3(NSPLIT, 64, B_), 256, 0, stream>>>(Qhi, Qlo, Khi, Klo, Vt, Pacc, Pm, Pl);

    // 4. Combine L-splits
    combine2<<<dim3(1024), 256, 0, stream>>>(Pacc, Pm, Pl, Ao);

    // 5. Output projection (fp32)
    proj_o<<<dim3(8, 8, 1), 256, 0, stream>>>(Ao, Wo, bo, out);
}

// Round 3
// 174.906 us; speedup vs baseline: 1.8955x; 1.0897x over previous
//
#include <hip/hip_runtime.h>
#include <math.h>

// Problem constants
#define B_   2
#define S_   256
#define E_   512
#define H_   8
#define DH_  64
#define LTOT   8192   // total KV rows per batch (TC*H + S*H)
#define LCACHE 6144   // TC*H
#define LNEW   2048   // S*H
#define NSPLIT 4      // L-splits across blocks (x4 waves inside block)

#define QSCALE (0.125f * 1.44269504088896f)   // 1/sqrt(DH) * log2(e)

typedef __attribute__((ext_vector_type(8))) short bf16x8;
typedef __attribute__((ext_vector_type(4))) float f32x4;

__device__ __forceinline__ ushort f2bf(float f) {             // RTN f32->bf16
    unsigned u = __float_as_uint(f);
    return (ushort)((u + 0x7fffu + ((u >> 16) & 1u)) >> 16);
}
__device__ __forceinline__ void split_hilo(float v, ushort& h, ushort& l) {
    h = f2bf(v);
    l = f2bf(v - __uint_as_float((unsigned)h << 16));
}

// ---------------------------------------------------------------------------
// convert_hilo: fp32 -> bf16 hi/lo for x and the 4 weight matrices.
// grid (32, 5); each tensor is 262144 floats = 65536 float4.
// ---------------------------------------------------------------------------
__global__ __launch_bounds__(256) void convert_hilo(
    const float* __restrict__ x,  const float* __restrict__ Wq,
    const float* __restrict__ Wk, const float* __restrict__ Wv,
    const float* __restrict__ Wo,
    ushort* __restrict__ xh,  ushort* __restrict__ xl,
    ushort* __restrict__ Wqh, ushort* __restrict__ Wql,
    ushort* __restrict__ Wkh, ushort* __restrict__ Wkl,
    ushort* __restrict__ Wvh, ushort* __restrict__ Wvl,
    ushort* __restrict__ Woh, ushort* __restrict__ Wol)
{
    const int z = blockIdx.y;
    const float* src; ushort* dh; ushort* dl;
    if (z == 0)      { src = x;  dh = xh;  dl = xl;  }
    else if (z == 1) { src = Wq; dh = Wqh; dl = Wql; }
    else if (z == 2) { src = Wk; dh = Wkh; dl = Wkl; }
    else if (z == 3) { src = Wv; dh = Wvh; dl = Wvl; }
    else             { src = Wo; dh = Woh; dl = Wol; }

    for (int i = blockIdx.x * 256 + threadIdx.x; i < 65536; i += 32 * 256) {
        const float4 v = reinterpret_cast<const float4*>(src)[i];
        ushort4 h, l;
        split_hilo(v.x, h.x, l.x); split_hilo(v.y, h.y, l.y);
        split_hilo(v.z, h.z, l.z); split_hilo(v.w, h.w, l.w);
        reinterpret_cast<ushort4*>(dh)[i] = h;
        reinterpret_cast<ushort4*>(dl)[i] = l;
    }
}

// ---------------------------------------------------------------------------
// prep_kcache: K cache fp32 [B][6144][64] -> Khi/Klo rows 0..6143. grid (48,B)
// ---------------------------------------------------------------------------
__global__ __launch_bounds__(256) void prep_kcache(
    const float* __restrict__ Kc, ushort* __restrict__ Khi, ushort* __restrict__ Klo)
{
    const int b = blockIdx.y;
    const float* src = Kc + (size_t)b * 393216;
    ushort* dh = Khi + (size_t)b * 524288;
    ushort* dl = Klo + (size_t)b * 524288;
    for (int i = blockIdx.x * 256 + threadIdx.x; i < 98304; i += 48 * 256) {
        const float4 v = reinterpret_cast<const float4*>(src)[i];
        ushort4 h, l;
        split_hilo(v.x, h.x, l.x); split_hilo(v.y, h.y, l.y);
        split_hilo(v.z, h.z, l.z); split_hilo(v.w, h.w, l.w);
        reinterpret_cast<ushort4*>(dh)[i] = h;
        reinterpret_cast<ushort4*>(dl)[i] = l;
    }
}

// ---------------------------------------------------------------------------
// proj_body: MFMA NT GEMM, C = x @ W^T + bias, M=N=K=512, bf16 hi/lo 3-term.
// A = W rows (output dim), B = x rows (token). D: col=lane&15 -> token,
// row(reg) -> 4 consecutive output dims => contiguous epilogue stores.
// Block: 256 thr = 4 waves (2x2), block tile 64(M)x64(N), wave tile 32x32.
// mode 0: Q  (scaled hi/lo -> dh/dl, [b][2048][64] flat)
// mode 1: K  (hi/lo -> dh/dl at rows 6144.. of [b][8192][64])
// mode 2: V  (single bf16 -> dh, [b][2048][64] flat)
// mode 3: O  (fp32 -> df, [512][512])
// ---------------------------------------------------------------------------
__device__ __forceinline__ void proj_body(
    const ushort* __restrict__ Ah, const ushort* __restrict__ Al,
    const ushort* __restrict__ Bh, const ushort* __restrict__ Bl,
    const float* __restrict__ bias, const int mode,
    ushort* __restrict__ dh, ushort* __restrict__ dl, float* __restrict__ df)
{
    const int tid = threadIdx.x;
    const int wv = tid >> 6, lane = tid & 63;
    const int lr = lane & 15, lg = lane >> 4;
    const int m0 = blockIdx.y * 64 + (wv & 1) * 32;   // token base
    const int n0 = blockIdx.x * 64 + (wv >> 1) * 32;  // output-dim base

    f32x4 acc[2][2];
#pragma unroll
    for (int mi = 0; mi < 2; ++mi)
#pragma unroll
        for (int ni = 0; ni < 2; ++ni) acc[mi][ni] = (f32x4){0.f, 0.f, 0.f, 0.f};

    const ushort* pa[2] = { Ah + (size_t)(n0 + lr) * 512 + lg * 8,
                            Ah + (size_t)(n0 + 16 + lr) * 512 + lg * 8 };
    const ushort* qa[2] = { Al + (size_t)(n0 + lr) * 512 + lg * 8,
                            Al + (size_t)(n0 + 16 + lr) * 512 + lg * 8 };
    const ushort* pb[2] = { Bh + (size_t)(m0 + lr) * 512 + lg * 8,
                            Bh + (size_t)(m0 + 16 + lr) * 512 + lg * 8 };
    const ushort* qb[2] = { Bl + (size_t)(m0 + lr) * 512 + lg * 8,
                            Bl + (size_t)(m0 + 16 + lr) * 512 + lg * 8 };

#pragma unroll 4
    for (int k0 = 0; k0 < 512; k0 += 32) {
        bf16x8 ah[2], al[2], bh[2], bl[2];
#pragma unroll
        for (int t = 0; t < 2; ++t) {
            ah[t] = *reinterpret_cast<const bf16x8*>(pa[t] + k0);
            al[t] = *reinterpret_cast<const bf16x8*>(qa[t] + k0);
            bh[t] = *reinterpret_cast<const bf16x8*>(pb[t] + k0);
            bl[t] = *reinterpret_cast<const bf16x8*>(qb[t] + k0);
        }
#pragma unroll
        for (int mi = 0; mi < 2; ++mi)
#pragma unroll
            for (int ni = 0; ni < 2; ++ni) {
                acc[mi][ni] = __builtin_amdgcn_mfma_f32_16x16x32_bf16(ah[ni], bh[mi], acc[mi][ni], 0, 0, 0);
                acc[mi][ni] = __builtin_amdgcn_mfma_f32_16x16x32_bf16(ah[ni], bl[mi], acc[mi][ni], 0, 0, 0);
                acc[mi][ni] = __builtin_amdgcn_mfma_f32_16x16x32_bf16(al[ni], bh[mi], acc[mi][ni], 0, 0, 0);
            }
    }

#pragma unroll
    for (int mi = 0; mi < 2; ++mi)
#pragma unroll
        for (int ni = 0; ni < 2; ++ni) {
            const int tok = m0 + mi * 16 + lr;
            const int e   = n0 + ni * 16 + lg * 4;
            const float4 bb = *reinterpret_cast<const float4*>(&bias[e]);
            float v0 = acc[mi][ni].x + bb.x, v1 = acc[mi][ni].y + bb.y;
            float v2 = acc[mi][ni].z + bb.z, v3 = acc[mi][ni].w + bb.w;
            const int b = tok >> 8, s = tok & 255;
            if (mode == 0) {
                v0 *= QSCALE; v1 *= QSCALE; v2 *= QSCALE; v3 *= QSCALE;
                ushort4 h, l;
                split_hilo(v0, h.x, l.x); split_hilo(v1, h.y, l.y);
                split_hilo(v2, h.z, l.z); split_hilo(v3, h.w, l.w);
                const size_t off = (size_t)b * 131072 + s * 512 + e;
                *reinterpret_cast<ushort4*>(dh + off) = h;
                *reinterpret_cast<ushort4*>(dl + off) = l;
            } else if (mode == 1) {
                ushort4 h, l;
                split_hilo(v0, h.x, l.x); split_hilo(v1, h.y, l.y);
                split_hilo(v2, h.z, l.z); split_hilo(v3, h.w, l.w);
                const size_t off = (size_t)b * 524288 + 393216 + s * 512 + e;
                *reinterpret_cast<ushort4*>(dh + off) = h;
                *reinterpret_cast<ushort4*>(dl + off) = l;
            } else if (mode == 2) {
                ushort4 h;
                h.x = f2bf(v0); h.y = f2bf(v1); h.z = f2bf(v2); h.w = f2bf(v3);
                const size_t off = (size_t)b * 131072 + s * 512 + e;
                *reinterpret_cast<ushort4*>(dh + off) = h;
            } else {
                float4 o; o.x = v0; o.y = v1; o.z = v2; o.w = v3;
                *reinterpret_cast<float4*>(df + (size_t)tok * 512 + e) = o;
            }
        }
}

__global__ __launch_bounds__(256) void proj_qkv_mfma(
    const ushort* __restrict__ Wqh, const ushort* __restrict__ Wql,
    const ushort* __restrict__ Wkh, const ushort* __restrict__ Wkl,
    const ushort* __restrict__ Wvh, const ushort* __restrict__ Wvl,
    const ushort* __restrict__ xh,  const ushort* __restrict__ xl,
    const float* __restrict__ bq, const float* __restrict__ bk, const float* __restrict__ bv,
    ushort* __restrict__ Qhi, ushort* __restrict__ Qlo,
    ushort* __restrict__ Khi, ushort* __restrict__ Klo,
    ushort* __restrict__ Vnb)
{
    if (blockIdx.z == 0)      proj_body(Wqh, Wql, xh, xl, bq, 0, Qhi, Qlo, nullptr);
    else if (blockIdx.z == 1) proj_body(Wkh, Wkl, xh, xl, bk, 1, Khi, Klo, nullptr);
    else                      proj_body(Wvh, Wvl, xh, xl, bv, 2, Vnb, nullptr, nullptr);
}

__global__ __launch_bounds__(256) void proj_o_mfma(
    const ushort* __restrict__ Woh, const ushort* __restrict__ Wol,
    const ushort* __restrict__ Aoh, const ushort* __restrict__ Aol,
    const float* __restrict__ bo, float* __restrict__ out)
{
    proj_body(Woh, Wol, Aoh, Aol, bo, 3, nullptr, nullptr, out);
}

// ---------------------------------------------------------------------------
// vt_kernel: V (cache fp32 / new bf16) -> Vt bf16 [B][64][8192] (dim-major)
// grid (128, B); 64-key x 64-dim tile per block via LDS transpose.
// ---------------------------------------------------------------------------
__global__ __launch_bounds__(256) void vt_kernel(
    const float* __restrict__ Vc, const ushort* __restrict__ Vnb, ushort* __restrict__ Vt)
{
    __shared__ ushort sT[64][68];   // [dim][key]
    const int kt = blockIdx.x, b = blockIdx.y, tid = threadIdx.x;
    const int key0 = kt * 64;
#pragma unroll
    for (int it = 0; it < 4; ++it) {
        const int id = it * 256 + tid;          // 0..1023 4-elem slots
        const int row = id >> 4, c4 = (id & 15) << 2;
        const int key = key0 + row;
        if (key < LCACHE) {
            const float4 v = *reinterpret_cast<const float4*>(
                &Vc[((size_t)b * LCACHE + key) * 64 + c4]);
            sT[c4+0][row] = f2bf(v.x); sT[c4+1][row] = f2bf(v.y);
            sT[c4+2][row] = f2bf(v.z); sT[c4+3][row] = f2bf(v.w);
        } else {
            const ushort4 v = *reinterpret_cast<const ushort4*>(
                &Vnb[((size_t)b * LNEW + (key - LCACHE)) * 64 + c4]);
            sT[c4+0][row] = v.x; sT[c4+1][row] = v.y;
            sT[c4+2][row] = v.z; sT[c4+3][row] = v.w;
        }
    }
    __syncthreads();
#pragma unroll
    for (int it = 0; it < 4; ++it) {
        const int id = it * 256 + tid;          // 0..1023 ushort4 slots
        const int d = id >> 4, ku = (id & 15) << 2;
        ushort4 o;
        o.x = sT[d][ku]; o.y = sT[d][ku+1]; o.z = sT[d][ku+2]; o.w = sT[d][ku+3];
        *reinterpret_cast<ushort4*>(&Vt[((size_t)b * 64 + d) * LTOT + key0 + ku]) = o;
    }
}

// ---------------------------------------------------------------------------
// attn_mfma: flash attention with MFMA (scores in log2 domain; Q pre-scaled
// by QSCALE so exp == exp2). Each wave: 32 q-rows, private 512-key chunk.
// grid (NSPLIT, 64, B), 256 threads.
// ---------------------------------------------------------------------------
__global__ __launch_bounds__(256) void attn_mfma(
    const ushort* __restrict__ Qhi, const ushort* __restrict__ Qlo,
    const ushort* __restrict__ Khi, const ushort* __restrict__ Klo,
    const ushort* __restrict__ Vt,
    float* __restrict__ Pacc, float* __restrict__ Pm, float* __restrict__ Pl)
{
    __shared__ float sAcc[4][32][68];
    __shared__ float sM[4][32];
    __shared__ float sL[4][32];

    const int tid = threadIdx.x;
    const int wv = tid >> 6, lane = tid & 63;
    const int lr = lane & 15, lg = lane >> 4;
    const int split = blockIdx.x, qb = blockIdx.y, b = blockIdx.z;

    bf16x8 qh[2][2], ql[2][2];
    {
        const int qrow0 = b * 2048 + qb * 32 + lr;
#pragma unroll
        for (int q = 0; q < 2; ++q)
#pragma unroll
            for (int h = 0; h < 2; ++h) {
                const int off = (qrow0 + q * 16) * 64 + h * 32 + lg * 8;
                qh[q][h] = *reinterpret_cast<const bf16x8*>(Qhi + off);
                ql[q][h] = *reinterpret_cast<const bf16x8*>(Qlo + off);
            }
    }

    const int kchunk = LTOT / NSPLIT / 4;            // 512 keys per wave
    const int kbase  = split * (LTOT / NSPLIT) + wv * kchunk;
    const int NT     = kchunk / 32;                  // 16 tiles of 32 keys
    const int krow0  = kbase + (lr & 3) + ((lr >> 2) << 3);   // permuted A row
    const ushort* kh_p = Khi + (size_t)b * LTOT * 64 + krow0 * 64 + lg * 8;
    const ushort* kl_p = Klo + (size_t)b * LTOT * 64 + krow0 * 64 + lg * 8;
    const ushort* vt_p = Vt  + (size_t)b * 64 * LTOT + (size_t)lr * LTOT + kbase + lg * 8;

    f32x4 acc[2][4];
#pragma unroll
    for (int q = 0; q < 2; ++q)
#pragma unroll
        for (int dt = 0; dt < 4; ++dt) acc[q][dt] = (f32x4){0.f, 0.f, 0.f, 0.f};
    float m0 = -INFINITY, m1 = -INFINITY, l0 = 0.f, l1 = 0.f;

    for (int t = 0; t < NT; ++t) {
        const ushort* kh = kh_p + t * 32 * 64;
        const ushort* kl = kl_p + t * 32 * 64;
        bf16x8 kf[2][2], lf[2][2], vf[4];
#pragma unroll
        for (int st = 0; st < 2; ++st)
#pragma unroll
            for (int h = 0; h < 2; ++h) {
                kf[st][h] = *reinterpret_cast<const bf16x8*>(kh + st * 4 * 64 + h * 32);
                lf[st][h] = *reinterpret_cast<const bf16x8*>(kl + st * 4 * 64 + h * 32);
            }
#pragma unroll
        for (int dt = 0; dt < 4; ++dt)
            vf[dt] = *reinterpret_cast<const bf16x8*>(vt_p + (size_t)dt * 16 * LTOT + t * 32);

#pragma unroll
        for (int q = 0; q < 2; ++q) {
            f32x4 s0 = {0.f,0.f,0.f,0.f}, s1 = {0.f,0.f,0.f,0.f};
#pragma unroll
            for (int h = 0; h < 2; ++h) {
                s0 = __builtin_amdgcn_mfma_f32_16x16x32_bf16(kf[0][h], qh[q][h], s0, 0, 0, 0);
                s0 = __builtin_amdgcn_mfma_f32_16x16x32_bf16(kf[0][h], ql[q][h], s0, 0, 0, 0);
                s0 = __builtin_amdgcn_mfma_f32_16x16x32_bf16(lf[0][h], qh[q][h], s0, 0, 0, 0);
                s1 = __builtin_amdgcn_mfma_f32_16x16x32_bf16(kf[1][h], qh[q][h], s1, 0, 0, 0);
                s1 = __builtin_amdgcn_mfma_f32_16x16x32_bf16(kf[1][h], ql[q][h], s1, 0, 0, 0);
                s1 = __builtin_amdgcn_mfma_f32_16x16x32_bf16(lf[1][h], qh[q][h], s1, 0, 0, 0);
            }
            float& mq = q ? m1 : m0;
            float& lq = q ? l1 : l0;
            float tm = fmaxf(fmaxf(fmaxf(s0.x, s0.y), fmaxf(s0.z, s0.w)),
                             fmaxf(fmaxf(s1.x, s1.y), fmaxf(s1.z, s1.w)));
            tm = fmaxf(tm, __shfl_xor(tm, 16));
            tm = fmaxf(tm, __shfl_xor(tm, 32));
            const float mn = fmaxf(mq, tm);
            const float corr = __builtin_exp2f(mq - mn);
            float p[8];
            p[0] = __builtin_exp2f(s0.x - mn); p[1] = __builtin_exp2f(s0.y - mn);
            p[2] = __builtin_exp2f(s0.z - mn); p[3] = __builtin_exp2f(s0.w - mn);
            p[4] = __builtin_exp2f(s1.x - mn); p[5] = __builtin_exp2f(s1.y - mn);
            p[6] = __builtin_exp2f(s1.z - mn); p[7] = __builtin_exp2f(s1.w - mn);
            float ps = ((p[0]+p[1]) + (p[2]+p[3])) + ((p[4]+p[5]) + (p[6]+p[7]));
            ps += __shfl_xor(ps, 16);
            ps += __shfl_xor(ps, 32);
            lq = lq * corr + ps; mq = mn;

            union { bf16x8 v; ushort u[8]; } pf;
#pragma unroll
            for (int j = 0; j < 8; ++j) pf.u[j] = f2bf(p[j]);
#pragma unroll
            for (int dt = 0; dt < 4; ++dt) {
                f32x4 a = acc[q][dt];
                a.x *= corr; a.y *= corr; a.z *= corr; a.w *= corr;
                acc[q][dt] = __builtin_amdgcn_mfma_f32_16x16x32_bf16(vf[dt], pf.v, a, 0, 0, 0);
            }
        }
    }

    // per-wave partials -> LDS   (C/D: col=lane&15 -> qrow, row -> dim)
#pragma unroll
    for (int q = 0; q < 2; ++q)
#pragma unroll
        for (int dt = 0; dt < 4; ++dt) {
            float4 o; o.x = acc[q][dt].x; o.y = acc[q][dt].y; o.z = acc[q][dt].z; o.w = acc[q][dt].w;
            *reinterpret_cast<float4*>(&sAcc[wv][q * 16 + lr][dt * 16 + lg * 4]) = o;
        }
    if (lg == 0) {
        sM[wv][lr] = m0;      sM[wv][16 + lr] = m1;
        sL[wv][lr] = l0;      sL[wv][16 + lr] = l1;
    }
    __syncthreads();

    // combine 4 waves: thread -> (qrow, 8-dim group)
    {
        const int qrow = tid >> 3, dg = tid & 7;
        float mw[4], ms = -INFINITY;
#pragma unroll
        for (int w = 0; w < 4; ++w) { mw[w] = sM[w][qrow]; ms = fmaxf(ms, mw[w]); }
        float den = 0.f;
        float num[8] = {};
#pragma unroll
        for (int w = 0; w < 4; ++w) {
            const float e = __builtin_exp2f(mw[w] - ms);
            den = fmaf(sL[w][qrow], e, den);
            const float4 a0 = *reinterpret_cast<const float4*>(&sAcc[w][qrow][dg * 8]);
            const float4 a1 = *reinterpret_cast<const float4*>(&sAcc[w][qrow][dg * 8 + 4]);
            num[0] = fmaf(a0.x, e, num[0]); num[1] = fmaf(a0.y, e, num[1]);
            num[2] = fmaf(a0.z, e, num[2]); num[3] = fmaf(a0.w, e, num[3]);
            num[4] = fmaf(a1.x, e, num[4]); num[5] = fmaf(a1.y, e, num[5]);
            num[6] = fmaf(a1.z, e, num[6]); num[7] = fmaf(a1.w, e, num[7]);
        }
        const int row_g = b * 2048 + qb * 32 + qrow;
        float* dst = Pacc + ((size_t)row_g * NSPLIT + split) * 64 + dg * 8;
        float4 o0 = {num[0], num[1], num[2], num[3]};
        float4 o1 = {num[4], num[5], num[6], num[7]};
        *reinterpret_cast<float4*>(dst)     = o0;
        *reinterpret_cast<float4*>(dst + 4) = o1;
        if (dg == 0) {
            Pm[(size_t)row_g * NSPLIT + split] = ms;
            Pl[(size_t)row_g * NSPLIT + split] = den;
        }
    }
}

// Combine the NSPLIT partial chunks per q-row; emit Ao as bf16 hi/lo.
__global__ __launch_bounds__(256) void combine2(
    const float* __restrict__ Pacc, const float* __restrict__ Pm,
    const float* __restrict__ Pl, ushort* __restrict__ Aoh, ushort* __restrict__ Aol)
{
    const int g = blockIdx.x * 256 + threadIdx.x;   // 0..262143
    const int row = g >> 6, d = g & 63;
    float mv[NSPLIT], ms = -INFINITY;
#pragma unroll
    for (int sp = 0; sp < NSPLIT; ++sp) { mv[sp] = Pm[row * NSPLIT + sp]; ms = fmaxf(ms, mv[sp]); }
    float num = 0.f, den = 0.f;
#pragma unroll
    for (int sp = 0; sp < NSPLIT; ++sp) {
        const float e = __builtin_exp2f(mv[sp] - ms);
        num = fmaf(Pacc[((size_t)row * NSPLIT + sp) * 64 + d], e, num);
        den = fmaf(Pl[row * NSPLIT + sp], e, den);
    }
    ushort h, l;
    split_hilo(num / den, h, l);
    Aoh[g] = h; Aol[g] = l;
}

// ---------------------------------------------------------------------------
extern "C" void kernel_launch(void* const* d_in, const int* in_sizes, int n_in,
                              void* d_out, int out_size, void* d_ws, size_t ws_size,
                              hipStream_t stream)
{
    const float* x  = (const float*)d_in[0];
    const float* kc = (const float*)d_in[1];
    const float* vc = (const float*)d_in[2];
    const float* Wq = (const float*)d_in[3];
    const float* bq = (const float*)d_in[4];
    const float* Wk = (const float*)d_in[5];
    const float* bk = (const float*)d_in[6];
    const float* Wv = (const float*)d_in[7];
    const float* bv = (const float*)d_in[8];
    const float* Wo = (const float*)d_in[9];
    const float* bo = (const float*)d_in[10];
    float* out = (float*)d_out;

    ushort* us  = (ushort*)d_ws;
    ushort* Khi = us;                   // 1048576
    ushort* Klo = us + 1048576;         // 1048576
    ushort* Vt  = us + 2097152;         // 1048576
    ushort* Qhi = us + 3145728;         //  262144
    ushort* Qlo = us + 3407872;         //  262144
    ushort* xh  = us + 3670016;         //  262144
    ushort* xl  = us + 3932160;         //  262144
    ushort* Wqh = us + 4194304;         //  262144
    ushort* Wql = us + 4456448;
    ushort* Wkh = us + 4718592;
    ushort* Wkl = us + 4980736;
    ushort* Wvh = us + 5242880;
    ushort* Wvl = us + 5505024;
    ushort* Woh = us + 5767168;
    ushort* Wol = us + 6029312;
    ushort* Vnb = us + 6291456;         //  262144
    ushort* Aoh = us + 6553600;         //  262144
    ushort* Aol = us + 6815744;         //  262144 -> ends 7077888 us
    float*  fs  = (float*)(us + 7077888);
    float*  Pacc = fs;                  // 1048576 f
    float*  Pm   = fs + 1048576;        //   16384 f
    float*  Pl   = fs + 1064960;        //   16384 f -> total ~18.5 MB

    // 1. Convert x and weights to bf16 hi/lo; K cache to hi/lo
    convert_hilo<<<dim3(32, 5), 256, 0, stream>>>(
        x, Wq, Wk, Wv, Wo, xh, xl, Wqh, Wql, Wkh, Wkl, Wvh, Wvl, Woh, Wol);
    prep_kcache<<<dim3(48, B_), 256, 0, stream>>>(kc, Khi, Klo);

    // 2. QKV projections (MFMA, hi/lo) -> Qhi/Qlo, Khi/Klo rows 6144.., Vnb
    proj_qkv_mfma<<<dim3(8, 8, 3), 256, 0, stream>>>(
        Wqh, Wql, Wkh, Wkl, Wvh, Wvl, xh, xl, bq, bk, bv, Qhi, Qlo, Khi, Klo, Vnb);

    // 3. V transpose to dim-major bf16
    vt_kernel<<<dim3(128, B_), 256, 0, stream>>>(vc, Vnb, Vt);

    // 4. MFMA flash attention partials
    attn_mfma<<<dim3(NSPLIT, 64, B_), 256, 0, stream>>>(Qhi, Qlo, Khi, Klo, Vt, Pacc, Pm, Pl);

    // 5. Combine L-splits -> Ao (bf16 hi/lo)
    combine2<<<dim3(1024), 256, 0, stream>>>(Pacc, Pm, Pl, Aoh, Aol);

    // 6. Output projection (MFMA)
    proj_o_mfma<<<dim3(8, 8), 256, 0, stream>>>(Woh, Wol, Aoh, Aol, bo, out);
}